// Round 4
// baseline (4738.530 us; speedup 1.0000x reference)
//
#include <hip/hip_runtime.h>

// 2D acoustic FDTD, temporally blocked, register-resident bands.
// KT=16 steps/launch, halo=KT. 8 full-width strips x B blocks, 1024 thr.
// Each wave owns 4 consecutive rows in registers; only band top/bottom rows
// go through LDS (ping-pong, compile-time buffer index via 2-step unroll).
// Lateral neighbors via DPP wave_shr:1/wave_shl:1 (bound_ctrl = domain edge).
// R4 vs R3: amdgpu_waves_per_eu(4,4) pins the 128-VGPR budget (R2/R3 were
// capped at 64 -> scratch spill in the step loop, 106us/dispatch); un[] gone
// (in-place leapfrog + role swap); receiver output buffered in LDS, flushed
// once (no per-step global-store drain at the barrier).

#define HH 256
#define WW 256
#define KT 16                 // time steps per launch == halo rows
#define SHR 32                // strip interior height
#define NSTRIP (HH / SHR)     // 8
#define NSLOT 16              // row-slots (= waves) per block
#define RPT 4                 // rows per thread (band height)
#define NTH 1024
#define C2SCALE 1.0e-4f       // DT/DX
#define NRMAX 128

__device__ __forceinline__ float dpp_west(float v) {
    // lane i <- lane i-1 ; lane 0 <- 0   (wave_shr:1, bound_ctrl:1)
    return __int_as_float(__builtin_amdgcn_mov_dpp(__float_as_int(v), 0x138, 0xf, 0xf, true));
}
__device__ __forceinline__ float dpp_east(float v) {
    // lane i <- lane i+1 ; lane 63 <- 0  (wave_shl:1, bound_ctrl:1)
    return __int_as_float(__builtin_amdgcn_mov_dpp(__float_as_int(v), 0x130, 0xf, 0xf, true));
}

// one leapfrog row: DST = 2*CC - DST + CI * lap(NN, CC, SS)   (DST aliases pv)
#define LAPROW(DST, NN, CC, SS, CI)                                          \
    {                                                                        \
        const float wl_ = dpp_west((CC).w);                                  \
        const float er_ = dpp_east((CC).x);                                  \
        float lx_ = (NN).x + (SS).x + wl_    + (CC).y - 4.0f * (CC).x;       \
        float ly_ = (NN).y + (SS).y + (CC).x + (CC).z - 4.0f * (CC).y;       \
        float lz_ = (NN).z + (SS).z + (CC).y + (CC).w - 4.0f * (CC).z;       \
        float lw_ = (NN).w + (SS).w + (CC).z + er_    - 4.0f * (CC).w;       \
        (DST).x = 2.0f * (CC).x - (DST).x + (CI).x * lx_;                    \
        (DST).y = 2.0f * (CC).y - (DST).y + (CI).y * ly_;                    \
        (DST).z = 2.0f * (CC).z - (DST).z + (CI).z * lz_;                    \
        (DST).w = 2.0f * (CC).w - (DST).w + (CI).w * lw_;                    \
    }

#define EMIT1(E, UN)                                                          \
    { const int pk_ = (E); const int rr_ = (pk_ >> 2) & 3; const int c_ = pk_ & 3; \
      const float4 uu_ = (rr_ == 0) ? UN[0] : ((rr_ == 1) ? UN[1] : ((rr_ == 2) ? UN[2] : UN[3])); \
      const float v_ = (c_ == 0) ? uu_.x : ((c_ == 1) ? uu_.y : ((c_ == 2) ? uu_.z : uu_.w));      \
      obuf[sidx_][pk_ >> 4] = v_; }

// UO: current newest field; UN: previous field, overwritten with the new one.
// BS/BD: compile-time ping-pong LDS buffer indices.
#define STEP(UO, UN, BS, BD, SIDX)                                           \
    {                                                                        \
        const int sidx_ = (SIDX);                                            \
        float4 nin_  = make_float4(0.f, 0.f, 0.f, 0.f);                      \
        float4 sin_  = make_float4(0.f, 0.f, 0.f, 0.f);                      \
        if (!north_zero) nin_ = *(const float4*)&bnd[BS][rs - 1][1][xg];     \
        if (!south_zero) sin_ = *(const float4*)&bnd[BS][rs + 1][0][xg];     \
        LAPROW(UN[0], nin_,  UO[0], UO[1], c2[0]);                           \
        LAPROW(UN[3], UO[2], UO[3], sin_,  c2[3]);                           \
        LAPROW(UN[1], UO[0], UO[1], UO[2], c2[1]);                           \
        LAPROW(UN[2], UO[1], UO[2], UO[3], c2[2]);                           \
        if (mine_src) {                                                      \
            const float xi_ = xs[sidx_];                                     \
            if (srr == 0)      { if (sc==0) UN[0].x+=xi_; else if (sc==1) UN[0].y+=xi_; else if (sc==2) UN[0].z+=xi_; else UN[0].w+=xi_; } \
            else if (srr == 1) { if (sc==0) UN[1].x+=xi_; else if (sc==1) UN[1].y+=xi_; else if (sc==2) UN[1].z+=xi_; else UN[1].w+=xi_; } \
            else if (srr == 2) { if (sc==0) UN[2].x+=xi_; else if (sc==1) UN[2].y+=xi_; else if (sc==2) UN[2].z+=xi_; else UN[2].w+=xi_; } \
            else               { if (sc==0) UN[3].x+=xi_; else if (sc==1) UN[3].y+=xi_; else if (sc==2) UN[3].z+=xi_; else UN[3].w+=xi_; } \
        }                                                                    \
        *(float4*)&bnd[BD][rs][0][xg] = UN[0];                               \
        *(float4*)&bnd[BD][rs][1][xg] = UN[3];                               \
        if (cnt > 0) {                                                       \
            EMIT1(e0, UN);                                                   \
            if (cnt > 1) { EMIT1(e1, UN);                                    \
              if (cnt > 2) { EMIT1(e2, UN);                                  \
                if (cnt > 3) { EMIT1(e3, UN);                                \
                  if (cnt > 4) { EMIT1(e4, UN);                              \
                    if (cnt > 5) { EMIT1(e5, UN); } } } } }                  \
        }                                                                    \
    }

__global__ void __launch_bounds__(NTH, 4) __attribute__((amdgpu_waves_per_eu(4, 4)))
wave_chunk(const float* __restrict__ x, const float* __restrict__ vp,
           const int* __restrict__ src_y, const int* __restrict__ src_x,
           const int* __restrict__ rec_y, const int* __restrict__ rec_x,
           float* __restrict__ gcur, float* __restrict__ gprev,
           float* __restrict__ out, int t0, int nsteps, int B, int NR, int init)
{
    __shared__ float bnd[2][NSLOT][2][WW];   // 64 KB ping-pong boundary rows
    __shared__ float obuf[KT][NRMAX];        // 8 KB receiver samples
    __shared__ int   rec_s[NRMAX];
    __shared__ float xs[KT];

    const int strip = blockIdx.x;
    const int bb    = blockIdx.y;
    const int y0    = strip * SHR;
    const int lo    = max(0, y0 - KT);
    const int hi    = min(HH, y0 + SHR + KT);
    const int RL    = hi - lo;               // 48 or 64 region rows

    const int tid  = threadIdx.x;
    const int lane = tid & 63;
    const int rs   = tid >> 6;               // wave id == row slot
    const int xg   = lane * 4;
    const int r0   = rs * RPT;
    const int gy0  = lo + r0;

    float4 u[RPT], pv[RPT], c2[RPT];
    const size_t bbase = (size_t)bb * HH * WW;

    // ---- stage receiver coords (packed) + source chunk into LDS ----
    if (tid < NR)     rec_s[tid] = (rec_y[tid] << 8) | rec_x[tid];
    if (tid < nsteps) xs[tid] = x[(t0 + tid) * B + bb];

    // ---- load band (u,pv from global unless init; c2 from vp) ----
    #pragma unroll
    for (int i = 0; i < RPT; ++i) {
        const int r = r0 + i;
        if (r < RL) {
            const int gy = lo + r;
            const size_t gi = bbase + (size_t)gy * WW + xg;
            float4 v = *(const float4*)&vp[gy * WW + xg];
            float4 cc;
            cc.x = v.x * C2SCALE; cc.y = v.y * C2SCALE;
            cc.z = v.z * C2SCALE; cc.w = v.w * C2SCALE;
            cc.x *= cc.x; cc.y *= cc.y; cc.z *= cc.z; cc.w *= cc.w;
            c2[i] = cc;
            if (init) {
                u[i]  = make_float4(0.f, 0.f, 0.f, 0.f);
                pv[i] = make_float4(0.f, 0.f, 0.f, 0.f);
            } else {
                u[i]  = *(const float4*)&gcur[gi];
                pv[i] = *(const float4*)&gprev[gi];
            }
        } else {
            c2[i] = make_float4(0.f, 0.f, 0.f, 0.f);
            u[i]  = make_float4(0.f, 0.f, 0.f, 0.f);
            pv[i] = make_float4(0.f, 0.f, 0.f, 0.f);
        }
    }

    // ---- source ownership (static per launch) ----
    const int sy = src_y[bb];
    const int sx = src_x[bb];
    const int srr = sy - gy0;                        // 0..3 if mine
    const bool mine_src = (sy >= lo) && (sy < hi) &&
                          (srr >= 0) && (srr < RPT) && ((sx >> 2) == lane);
    const int sc = sx & 3;

    // ---- publish initial boundary rows (barrier also fences staging) ----
    *(float4*)&bnd[0][rs][0][xg] = u[0];
    *(float4*)&bnd[0][rs][1][xg] = u[RPT - 1];
    __syncthreads();

    // ---- receiver ownership: <=6 static slots per thread (LDS scan) ----
    int e0 = 0, e1 = 0, e2 = 0, e3 = 0, e4 = 0, e5 = 0, cnt = 0;
    for (int k = 0; k < NR; ++k) {
        const int rc = rec_s[k];                     // broadcast LDS read
        const int ry = rc >> 8;
        if (ry >= y0 && ry < y0 + SHR) {
            const int rr = ry - gy0;
            if (rr >= 0 && rr < RPT) {
                const int rx = rc & 255;
                if ((rx >> 2) == lane) {
                    const int pk = (k << 4) | (rr << 2) | (rx & 3);
                    if (cnt == 0) e0 = pk; else if (cnt == 1) e1 = pk;
                    else if (cnt == 2) e2 = pk; else if (cnt == 3) e3 = pk;
                    else if (cnt == 4) e4 = pk; else e5 = pk;
                    ++cnt;
                }
            }
        }
    }

    const bool north_zero = (rs == 0);
    const bool south_zero = (rs == NSLOT - 1) || (gy0 + RPT - 1 == HH - 1);

    // ---- time loop: 2 steps per iteration, role-swapped (nsteps is even) ----
    #pragma unroll 1
    for (int s = 0; s < nsteps; s += 2) {
        STEP(u, pv, 0, 1, s);        // newest now in pv
        __syncthreads();
        STEP(pv, u, 1, 0, s + 1);    // newest now in u
        __syncthreads();
    }
    // after an even number of steps: u = newest, pv = one-older. Same as ref.

    // ---- write back interior rows of both time levels ----
    #pragma unroll
    for (int i = 0; i < RPT; ++i) {
        const int r = r0 + i;
        const int gy = lo + r;
        if (r < RL && gy >= y0 && gy < y0 + SHR) {
            const size_t gi = bbase + (size_t)gy * WW + xg;
            *(float4*)&gcur[gi]  = u[i];
            *(float4*)&gprev[gi] = pv[i];
        }
    }

    // ---- flush receiver samples (single drain instead of per-step) ----
    for (int p = tid; p < KT * NRMAX; p += NTH) {
        const int s = p >> 7;          // p / 128
        const int k = p & 127;
        if (s < nsteps && k < NR) {
            const int rc = rec_s[k];
            const int ry = rc >> 8;
            if (ry >= y0 && ry < y0 + SHR) {
                out[(size_t)(t0 + s) * B * NR + (size_t)bb * NR + k] = obuf[s][k];
            }
        }
    }
}

extern "C" void kernel_launch(void* const* d_in, const int* in_sizes, int n_in,
                              void* d_out, int out_size, void* d_ws, size_t ws_size,
                              hipStream_t stream) {
    const float* x     = (const float*)d_in[0];
    const float* vp    = (const float*)d_in[1];
    const int* src_y   = (const int*)d_in[2];
    const int* src_x   = (const int*)d_in[3];
    const int* rec_y   = (const int*)d_in[4];
    const int* rec_x   = (const int*)d_in[5];

    const int B  = in_sizes[2];
    const int NR = in_sizes[4];
    const int NT = in_sizes[0] / B;

    float* gcur  = (float*)d_ws;
    float* gprev = gcur + (size_t)B * HH * WW;
    float* outp  = (float*)d_out;

    dim3 grid(NSTRIP, B), block(NTH);
    for (int t0 = 0; t0 < NT; t0 += KT) {
        const int ns = (NT - t0 < KT) ? (NT - t0) : KT;
        wave_chunk<<<grid, block, 0, stream>>>(x, vp, src_y, src_x, rec_y, rec_x,
                                               gcur, gprev, outp, t0, ns, B, NR,
                                               (t0 == 0) ? 1 : 0);
    }
}

// Round 5
// 1271.672 us; speedup vs baseline: 3.7262x; 3.7262x over previous
//
#include <hip/hip_runtime.h>

// 2D acoustic FDTD, temporally blocked, register-resident bands.
// KT=16 steps/launch, halo=KT. 8 full-width strips x B blocks, 1024 thr.
// Each wave owns 4 consecutive rows in NAMED float4 registers; only band
// top/bottom rows go through LDS (ping-pong, compile-time buffer index).
// Lateral neighbors via DPP wave_shr:1/wave_shl:1 (bound_ctrl = domain edge).
// R5 vs R4: no local arrays AT ALL (u0..u3,p0..p3,c20..c23 named vars) --
// R2-R4 kept demoting the band arrays to scratch (VGPR_Count 52-64, 127us
// dispatches, VALUBusy 0.6%); waves_per_eu(1,4) removes any VGPR cap.

#define HH 256
#define WW 256
#define KT 16                 // time steps per launch == halo rows
#define SHR 32                // strip interior height
#define NSTRIP (HH / SHR)     // 8
#define NSLOT 16              // row-slots (= waves) per block
#define RPT 4                 // rows per thread (band height)
#define NTH 1024
#define C2SCALE 1.0e-4f       // DT/DX
#define NRMAX 128

__device__ __forceinline__ float dpp_west(float v) {
    // lane i <- lane i-1 ; lane 0 <- 0   (wave_shr:1, bound_ctrl:1)
    return __int_as_float(__builtin_amdgcn_mov_dpp(__float_as_int(v), 0x138, 0xf, 0xf, true));
}
__device__ __forceinline__ float dpp_east(float v) {
    // lane i <- lane i+1 ; lane 63 <- 0  (wave_shl:1, bound_ctrl:1)
    return __int_as_float(__builtin_amdgcn_mov_dpp(__float_as_int(v), 0x130, 0xf, 0xf, true));
}

#define ZERO4 make_float4(0.f, 0.f, 0.f, 0.f)

// P = 2*C - P + CI * lap(N, C, S)     (in-place leapfrog, P aliases u_{t-1})
#define LAPROW(P, NN, CC, SS, CI)                                            \
    {                                                                        \
        const float wl_ = dpp_west((CC).w);                                  \
        const float er_ = dpp_east((CC).x);                                  \
        const float lx_ = (NN).x + (SS).x + wl_    + (CC).y - 4.0f * (CC).x; \
        const float ly_ = (NN).y + (SS).y + (CC).x + (CC).z - 4.0f * (CC).y; \
        const float lz_ = (NN).z + (SS).z + (CC).y + (CC).w - 4.0f * (CC).z; \
        const float lw_ = (NN).w + (SS).w + (CC).z + er_    - 4.0f * (CC).w; \
        (P).x = 2.0f * (CC).x - (P).x + (CI).x * lx_;                        \
        (P).y = 2.0f * (CC).y - (P).y + (CI).y * ly_;                        \
        (P).z = 2.0f * (CC).z - (P).z + (CI).z * lz_;                        \
        (P).w = 2.0f * (CC).w - (P).w + (CI).w * lw_;                        \
    }

#define INJECT(P) { if (sc == 0) (P).x += xi_; else if (sc == 1) (P).y += xi_; \
                    else if (sc == 2) (P).z += xi_; else (P).w += xi_; }

#define EMIT1(E, A0, A1, A2, A3)                                             \
    { const int pk_ = (E); const int rr_ = (pk_ >> 2) & 3; const int c_ = pk_ & 3; \
      const float4 uu_ = (rr_ == 0) ? (A0) : ((rr_ == 1) ? (A1) : ((rr_ == 2) ? (A2) : (A3))); \
      const float v_ = (c_ == 0) ? uu_.x : ((c_ == 1) ? uu_.y : ((c_ == 2) ? uu_.z : uu_.w));  \
      obuf[sidx_][pk_ >> 4] = v_; }

// One leapfrog step: newest currently in U*, previous in P*; after the step
// the newest is in P* (in-place). BS/BD: compile-time LDS ping-pong indices.
#define STEP(U0, U1, U2, U3, P0, P1, P2, P3, BS, BD, SIDX)                   \
    {                                                                        \
        const int sidx_ = (SIDX);                                            \
        float4 nin_ = ZERO4, sin_ = ZERO4;                                   \
        if (!north_zero) nin_ = *(const float4*)&bnd[BS][rs - 1][1][xg];     \
        if (!south_zero) sin_ = *(const float4*)&bnd[BS][rs + 1][0][xg];     \
        LAPROW(P0, nin_, U0, U1, c20);                                       \
        LAPROW(P3, U2, U3, sin_, c23);                                       \
        LAPROW(P1, U0, U1, U2, c21);                                         \
        LAPROW(P2, U1, U2, U3, c22);                                         \
        if (mine_src) {                                                      \
            const float xi_ = xs[sidx_];                                     \
            if (srr == 0)      INJECT(P0)                                    \
            else if (srr == 1) INJECT(P1)                                    \
            else if (srr == 2) INJECT(P2)                                    \
            else               INJECT(P3)                                    \
        }                                                                    \
        *(float4*)&bnd[BD][rs][0][xg] = P0;                                  \
        *(float4*)&bnd[BD][rs][1][xg] = P3;                                  \
        if (cnt > 0) {                                                       \
            EMIT1(e0, P0, P1, P2, P3);                                       \
            if (cnt > 1) { EMIT1(e1, P0, P1, P2, P3);                        \
              if (cnt > 2) { EMIT1(e2, P0, P1, P2, P3);                      \
                if (cnt > 3) { EMIT1(e3, P0, P1, P2, P3);                    \
                  if (cnt > 4) { EMIT1(e4, P0, P1, P2, P3);                  \
                    if (cnt > 5) { EMIT1(e5, P0, P1, P2, P3); } } } } }      \
        }                                                                    \
    }

#define LOADROW(I, U, P, C)                                                  \
    {                                                                        \
        const int r_ = r0 + (I);                                             \
        if (r_ < RL) {                                                       \
            const int gy_ = lo + r_;                                         \
            const size_t gi_ = bbase + (size_t)gy_ * WW + xg;                \
            const float4 v_ = *(const float4*)&vp[gy_ * WW + xg];            \
            (C).x = v_.x * C2SCALE; (C).y = v_.y * C2SCALE;                  \
            (C).z = v_.z * C2SCALE; (C).w = v_.w * C2SCALE;                  \
            (C).x *= (C).x; (C).y *= (C).y; (C).z *= (C).z; (C).w *= (C).w;  \
            if (init) { (U) = ZERO4; (P) = ZERO4; }                          \
            else { (U) = *(const float4*)&gcur[gi_];                         \
                   (P) = *(const float4*)&gprev[gi_]; }                      \
        } else { (C) = ZERO4; (U) = ZERO4; (P) = ZERO4; }                    \
    }

#define SAVEROW(I, U, P)                                                     \
    {                                                                        \
        const int r_ = r0 + (I);                                             \
        const int gy_ = lo + r_;                                             \
        if (r_ < RL && gy_ >= y0 && gy_ < y0 + SHR) {                        \
            const size_t gi_ = bbase + (size_t)gy_ * WW + xg;                \
            *(float4*)&gcur[gi_]  = (U);                                     \
            *(float4*)&gprev[gi_] = (P);                                     \
        }                                                                    \
    }

__global__ void __launch_bounds__(NTH) __attribute__((amdgpu_waves_per_eu(1, 4)))
wave_chunk(const float* __restrict__ x, const float* __restrict__ vp,
           const int* __restrict__ src_y, const int* __restrict__ src_x,
           const int* __restrict__ rec_y, const int* __restrict__ rec_x,
           float* __restrict__ gcur, float* __restrict__ gprev,
           float* __restrict__ out, int t0, int nsteps, int B, int NR, int init)
{
    __shared__ float bnd[2][NSLOT][2][WW];   // 64 KB ping-pong boundary rows
    __shared__ float obuf[KT][NRMAX];        // 8 KB receiver samples
    __shared__ int   rec_s[NRMAX];
    __shared__ float xs[KT];

    const int strip = blockIdx.x;
    const int bb    = blockIdx.y;
    const int y0    = strip * SHR;
    const int lo    = max(0, y0 - KT);
    const int hi    = min(HH, y0 + SHR + KT);
    const int RL    = hi - lo;               // 48 or 64 region rows

    const int tid  = threadIdx.x;
    const int lane = tid & 63;
    const int rs   = tid >> 6;               // wave id == row slot
    const int xg   = lane * 4;
    const int r0   = rs * RPT;
    const int gy0  = lo + r0;

    const size_t bbase = (size_t)bb * HH * WW;

    // ---- stage receiver coords (packed) + source chunk into LDS ----
    if (tid < NR)     rec_s[tid] = (rec_y[tid] << 8) | rec_x[tid];
    if (tid < nsteps) xs[tid] = x[(t0 + tid) * B + bb];

    // ---- band state: NAMED register variables only ----
    float4 u0, u1, u2, u3, p0, p1, p2, p3, c20, c21, c22, c23;
    LOADROW(0, u0, p0, c20);
    LOADROW(1, u1, p1, c21);
    LOADROW(2, u2, p2, c22);
    LOADROW(3, u3, p3, c23);

    // ---- source ownership (static per launch) ----
    const int sy = src_y[bb];
    const int sx = src_x[bb];
    const int srr = sy - gy0;                        // 0..3 if mine
    const bool mine_src = (sy >= lo) && (sy < hi) &&
                          (srr >= 0) && (srr < RPT) && ((sx >> 2) == lane);
    const int sc = sx & 3;

    // ---- publish initial boundary rows (barrier also fences staging) ----
    *(float4*)&bnd[0][rs][0][xg] = u0;
    *(float4*)&bnd[0][rs][1][xg] = u3;
    __syncthreads();

    // ---- receiver ownership: <=6 static slots per thread (LDS scan) ----
    int e0 = 0, e1 = 0, e2 = 0, e3 = 0, e4 = 0, e5 = 0, cnt = 0;
    for (int k = 0; k < NR; ++k) {
        const int rc = rec_s[k];                     // broadcast LDS read
        const int ry = rc >> 8;
        if (ry >= y0 && ry < y0 + SHR) {
            const int rr = ry - gy0;
            if (rr >= 0 && rr < RPT) {
                const int rx = rc & 255;
                if ((rx >> 2) == lane) {
                    const int pk = (k << 4) | (rr << 2) | (rx & 3);
                    if (cnt == 0) e0 = pk; else if (cnt == 1) e1 = pk;
                    else if (cnt == 2) e2 = pk; else if (cnt == 3) e3 = pk;
                    else if (cnt == 4) e4 = pk; else e5 = pk;
                    ++cnt;
                }
            }
        }
    }

    const bool north_zero = (rs == 0);
    const bool south_zero = (rs == NSLOT - 1) || (gy0 + RPT - 1 == HH - 1);

    // ---- time loop: 2 steps per iteration, role-swapped (nsteps is even) ----
    #pragma unroll 1
    for (int s = 0; s < nsteps; s += 2) {
        STEP(u0, u1, u2, u3, p0, p1, p2, p3, 0, 1, s);       // newest -> p*
        __syncthreads();
        STEP(p0, p1, p2, p3, u0, u1, u2, u3, 1, 0, s + 1);   // newest -> u*
        __syncthreads();
    }
    // after an even number of steps: u* = newest, p* = one-older (as ref).

    // ---- write back interior rows of both time levels ----
    SAVEROW(0, u0, p0);
    SAVEROW(1, u1, p1);
    SAVEROW(2, u2, p2);
    SAVEROW(3, u3, p3);

    // ---- flush receiver samples (single drain instead of per-step) ----
    for (int p = tid; p < KT * NRMAX; p += NTH) {
        const int s = p >> 7;          // p / 128
        const int k = p & 127;
        if (s < nsteps && k < NR) {
            const int rc = rec_s[k];
            const int ry = rc >> 8;
            if (ry >= y0 && ry < y0 + SHR) {
                out[(size_t)(t0 + s) * B * NR + (size_t)bb * NR + k] = obuf[s][k];
            }
        }
    }
}

extern "C" void kernel_launch(void* const* d_in, const int* in_sizes, int n_in,
                              void* d_out, int out_size, void* d_ws, size_t ws_size,
                              hipStream_t stream) {
    const float* x     = (const float*)d_in[0];
    const float* vp    = (const float*)d_in[1];
    const int* src_y   = (const int*)d_in[2];
    const int* src_x   = (const int*)d_in[3];
    const int* rec_y   = (const int*)d_in[4];
    const int* rec_x   = (const int*)d_in[5];

    const int B  = in_sizes[2];
    const int NR = in_sizes[4];
    const int NT = in_sizes[0] / B;

    float* gcur  = (float*)d_ws;
    float* gprev = gcur + (size_t)B * HH * WW;
    float* outp  = (float*)d_out;

    dim3 grid(NSTRIP, B), block(NTH);
    for (int t0 = 0; t0 < NT; t0 += KT) {
        const int ns = (NT - t0 < KT) ? (NT - t0) : KT;
        wave_chunk<<<grid, block, 0, stream>>>(x, vp, src_y, src_x, rec_y, rec_x,
                                               gcur, gprev, outp, t0, ns, B, NR,
                                               (t0 == 0) ? 1 : 0);
    }
}

// Round 6
// 828.936 us; speedup vs baseline: 5.7164x; 1.5341x over previous
//
#include <hip/hip_runtime.h>
#include <hip/hip_cooperative_groups.h>

namespace cg = cooperative_groups;

// 2D acoustic FDTD, persistent cooperative kernel with temporal blocking.
// One launch for all NT=600 steps: 8 full-width strips x B blocks, 1024 thr.
// Each wave owns 4 consecutive rows in NAMED float4 registers; band
// top/bottom rows exchange via LDS ping-pong each step; strips exchange
// halo rows via global memory + grid.sync() every KT=16 steps.
// Lateral neighbors via DPP wave_shr:1/wave_shl:1 (bound_ctrl = domain edge).
// R6 vs R5: 38 launches -> 1 cooperative launch (removes launch gaps);
// c2 / receiver-scan / source ownership computed once; inter-chunk exchange
// is halo-rows-only (8 KB/block instead of full-region reload).

#define HH 256
#define WW 256
#define KT 16                 // time steps per chunk == halo rows
#define SHR 32                // strip interior height
#define NSTRIP (HH / SHR)     // 8
#define NSLOT 16              // row-slots (= waves) per block
#define RPT 4                 // rows per thread (band height)
#define NTH 1024
#define C2SCALE 1.0e-4f       // DT/DX
#define NRMAX 128

__device__ __forceinline__ float dpp_west(float v) {
    // lane i <- lane i-1 ; lane 0 <- 0   (wave_shr:1, bound_ctrl:1)
    return __int_as_float(__builtin_amdgcn_mov_dpp(__float_as_int(v), 0x138, 0xf, 0xf, true));
}
__device__ __forceinline__ float dpp_east(float v) {
    // lane i <- lane i+1 ; lane 63 <- 0  (wave_shl:1, bound_ctrl:1)
    return __int_as_float(__builtin_amdgcn_mov_dpp(__float_as_int(v), 0x130, 0xf, 0xf, true));
}

#define ZERO4 make_float4(0.f, 0.f, 0.f, 0.f)

// P = 2*C - P + CI * lap(N, C, S)     (in-place leapfrog, P aliases u_{t-1})
#define LAPROW(P, NN, CC, SS, CI)                                            \
    {                                                                        \
        const float wl_ = dpp_west((CC).w);                                  \
        const float er_ = dpp_east((CC).x);                                  \
        const float lx_ = (NN).x + (SS).x + wl_    + (CC).y - 4.0f * (CC).x; \
        const float ly_ = (NN).y + (SS).y + (CC).x + (CC).z - 4.0f * (CC).y; \
        const float lz_ = (NN).z + (SS).z + (CC).y + (CC).w - 4.0f * (CC).z; \
        const float lw_ = (NN).w + (SS).w + (CC).z + er_    - 4.0f * (CC).w; \
        (P).x = 2.0f * (CC).x - (P).x + (CI).x * lx_;                        \
        (P).y = 2.0f * (CC).y - (P).y + (CI).y * ly_;                        \
        (P).z = 2.0f * (CC).z - (P).z + (CI).z * lz_;                        \
        (P).w = 2.0f * (CC).w - (P).w + (CI).w * lw_;                        \
    }

#define INJECT(P) { if (sc == 0) (P).x += xi_; else if (sc == 1) (P).y += xi_; \
                    else if (sc == 2) (P).z += xi_; else (P).w += xi_; }

#define EMIT1(E, A0, A1, A2, A3)                                             \
    { const int pk_ = (E); const int rr_ = (pk_ >> 2) & 3; const int c_ = pk_ & 3; \
      const float4 uu_ = (rr_ == 0) ? (A0) : ((rr_ == 1) ? (A1) : ((rr_ == 2) ? (A2) : (A3))); \
      const float v_ = (c_ == 0) ? uu_.x : ((c_ == 1) ? uu_.y : ((c_ == 2) ? uu_.z : uu_.w));  \
      obuf[sidx_][pk_ >> 4] = v_; }

// One leapfrog step: newest currently in U*, previous in P*; after the step
// the newest is in P* (in-place). BS/BD: compile-time LDS ping-pong indices.
#define STEP(U0, U1, U2, U3, P0, P1, P2, P3, BS, BD, SIDX)                   \
    {                                                                        \
        const int sidx_ = (SIDX);                                            \
        float4 nin_ = ZERO4, sin_ = ZERO4;                                   \
        if (!north_zero) nin_ = *(const float4*)&bnd[BS][rs - 1][1][xg];     \
        if (!south_zero) sin_ = *(const float4*)&bnd[BS][rs + 1][0][xg];     \
        LAPROW(P0, nin_, U0, U1, c20);                                       \
        LAPROW(P3, U2, U3, sin_, c23);                                       \
        LAPROW(P1, U0, U1, U2, c21);                                         \
        LAPROW(P2, U1, U2, U3, c22);                                         \
        if (mine_src) {                                                      \
            const float xi_ = xs[sidx_];                                     \
            if (srr == 0)      INJECT(P0)                                    \
            else if (srr == 1) INJECT(P1)                                    \
            else if (srr == 2) INJECT(P2)                                    \
            else               INJECT(P3)                                    \
        }                                                                    \
        *(float4*)&bnd[BD][rs][0][xg] = P0;                                  \
        *(float4*)&bnd[BD][rs][1][xg] = P3;                                  \
        if (cnt > 0) {                                                       \
            EMIT1(e0, P0, P1, P2, P3);                                       \
            if (cnt > 1) { EMIT1(e1, P0, P1, P2, P3);                        \
              if (cnt > 2) { EMIT1(e2, P0, P1, P2, P3);                      \
                if (cnt > 3) { EMIT1(e3, P0, P1, P2, P3);                    \
                  if (cnt > 4) { EMIT1(e4, P0, P1, P2, P3);                  \
                    if (cnt > 5) { EMIT1(e5, P0, P1, P2, P3); } } } } }      \
        }                                                                    \
    }

// c2 for one band row (loaded once; never changes)
#define LOADC2(I, C)                                                         \
    {                                                                        \
        const int r_ = r0 + (I);                                             \
        if (r_ < RL) {                                                       \
            const int gy_ = lo + r_;                                         \
            const float4 v_ = *(const float4*)&vp[gy_ * WW + xg];            \
            (C).x = v_.x * C2SCALE; (C).y = v_.y * C2SCALE;                  \
            (C).z = v_.z * C2SCALE; (C).w = v_.w * C2SCALE;                  \
            (C).x *= (C).x; (C).y *= (C).y; (C).z *= (C).z; (C).w *= (C).w;  \
        } else { (C) = ZERO4; }                                              \
    }

// write interior rows to global (inter-strip exchange payload)
#define SAVEROW(I, U, P)                                                     \
    {                                                                        \
        const int r_ = r0 + (I);                                             \
        const int gy_ = lo + r_;                                             \
        if (r_ < RL && gy_ >= y0 && gy_ < y0 + SHR) {                        \
            const size_t gi_ = bbase + (size_t)gy_ * WW + xg;                \
            *(float4*)&gcur[gi_]  = (U);                                     \
            *(float4*)&gprev[gi_] = (P);                                     \
        }                                                                    \
    }

// reload halo rows from neighbors' just-written interiors
#define RELOADROW(I, U, P)                                                   \
    {                                                                        \
        const int r_ = r0 + (I);                                             \
        const int gy_ = lo + r_;                                             \
        if (r_ < RL && (gy_ < y0 || gy_ >= y0 + SHR)) {                      \
            const size_t gi_ = bbase + (size_t)gy_ * WW + xg;                \
            (U) = *(const float4*)&gcur[gi_];                                \
            (P) = *(const float4*)&gprev[gi_];                               \
        }                                                                    \
    }

__global__ void __launch_bounds__(NTH) __attribute__((amdgpu_waves_per_eu(1, 4)))
wave_persist(const float* __restrict__ x, const float* __restrict__ vp,
             const int* __restrict__ src_y, const int* __restrict__ src_x,
             const int* __restrict__ rec_y, const int* __restrict__ rec_x,
             float* __restrict__ gcur, float* __restrict__ gprev,
             float* __restrict__ out, int NT, int B, int NR)
{
    cg::grid_group gg = cg::this_grid();

    __shared__ float bnd[2][NSLOT][2][WW];   // 64 KB ping-pong boundary rows
    __shared__ float obuf[KT][NRMAX];        // 8 KB receiver samples
    __shared__ int   rec_s[NRMAX];
    __shared__ float xs[KT];

    const int strip = blockIdx.x;
    const int bb    = blockIdx.y;
    const int y0    = strip * SHR;
    const int lo    = max(0, y0 - KT);
    const int hi    = min(HH, y0 + SHR + KT);
    const int RL    = hi - lo;               // 48 or 64 region rows

    const int tid  = threadIdx.x;
    const int lane = tid & 63;
    const int rs   = tid >> 6;               // wave id == row slot
    const int xg   = lane * 4;
    const int r0   = rs * RPT;
    const int gy0  = lo + r0;

    const size_t bbase = (size_t)bb * HH * WW;

    // ---- one-time setup ----
    if (tid < NR) rec_s[tid] = (rec_y[tid] << 8) | rec_x[tid];

    float4 u0 = ZERO4, u1 = ZERO4, u2 = ZERO4, u3 = ZERO4;
    float4 p0 = ZERO4, p1 = ZERO4, p2 = ZERO4, p3 = ZERO4;
    float4 c20, c21, c22, c23;
    LOADC2(0, c20); LOADC2(1, c21); LOADC2(2, c22); LOADC2(3, c23);

    const int sy = src_y[bb];
    const int sx = src_x[bb];
    const int srr = sy - gy0;                        // 0..3 if mine
    const bool mine_src = (sy >= lo) && (sy < hi) &&
                          (srr >= 0) && (srr < RPT) && ((sx >> 2) == lane);
    const int sc = sx & 3;

    __syncthreads();                                 // fence rec_s

    // receiver ownership: <=6 static slots per thread (LDS broadcast scan)
    int e0 = 0, e1 = 0, e2 = 0, e3 = 0, e4 = 0, e5 = 0, cnt = 0;
    for (int k = 0; k < NR; ++k) {
        const int rc = rec_s[k];
        const int ry = rc >> 8;
        if (ry >= y0 && ry < y0 + SHR) {
            const int rr = ry - gy0;
            if (rr >= 0 && rr < RPT) {
                const int rx = rc & 255;
                if ((rx >> 2) == lane) {
                    const int pk = (k << 4) | (rr << 2) | (rx & 3);
                    if (cnt == 0) e0 = pk; else if (cnt == 1) e1 = pk;
                    else if (cnt == 2) e2 = pk; else if (cnt == 3) e3 = pk;
                    else if (cnt == 4) e4 = pk; else e5 = pk;
                    ++cnt;
                }
            }
        }
    }

    const bool north_zero = (rs == 0);
    const bool south_zero = (rs == NSLOT - 1) || (gy0 + RPT - 1 == HH - 1);

    // ---- chunk loop: KT steps, then halo exchange through global ----
    for (int t0 = 0; t0 < NT; t0 += KT) {
        const int ns = (NT - t0 < KT) ? (NT - t0) : KT;   // 16 or 8 (even)

        if (tid < ns) xs[tid] = x[(t0 + tid) * B + bb];
        *(float4*)&bnd[0][rs][0][xg] = u0;
        *(float4*)&bnd[0][rs][1][xg] = u3;
        __syncthreads();

        #pragma unroll 1
        for (int s = 0; s < ns; s += 2) {
            STEP(u0, u1, u2, u3, p0, p1, p2, p3, 0, 1, s);       // newest -> p*
            __syncthreads();
            STEP(p0, p1, p2, p3, u0, u1, u2, u3, 1, 0, s + 1);   // newest -> u*
            __syncthreads();
        }
        // after an even number of steps: u* = newest, p* = one-older.

        // flush receiver samples for this chunk
        for (int p = tid; p < KT * NRMAX; p += NTH) {
            const int s = p >> 7;          // p / 128
            const int k = p & 127;
            if (s < ns && k < NR) {
                const int rc = rec_s[k];
                const int ry = rc >> 8;
                if (ry >= y0 && ry < y0 + SHR) {
                    out[(size_t)(t0 + s) * B * NR + (size_t)bb * NR + k] = obuf[s][k];
                }
            }
        }

        if (t0 + KT < NT) {
            // inter-strip halo exchange: write my interior, sync, read halo
            SAVEROW(0, u0, p0); SAVEROW(1, u1, p1);
            SAVEROW(2, u2, p2); SAVEROW(3, u3, p3);
            gg.sync();
            RELOADROW(0, u0, p0); RELOADROW(1, u1, p1);
            RELOADROW(2, u2, p2); RELOADROW(3, u3, p3);
        }
    }
}

extern "C" void kernel_launch(void* const* d_in, const int* in_sizes, int n_in,
                              void* d_out, int out_size, void* d_ws, size_t ws_size,
                              hipStream_t stream) {
    const float* x     = (const float*)d_in[0];
    const float* vp    = (const float*)d_in[1];
    const int* src_y   = (const int*)d_in[2];
    const int* src_x   = (const int*)d_in[3];
    const int* rec_y   = (const int*)d_in[4];
    const int* rec_x   = (const int*)d_in[5];

    int B  = in_sizes[2];
    int NR = in_sizes[4];
    int NT = in_sizes[0] / B;

    float* gcur  = (float*)d_ws;
    float* gprev = gcur + (size_t)B * HH * WW;
    float* outp  = (float*)d_out;

    void* args[] = { (void*)&x, (void*)&vp, (void*)&src_y, (void*)&src_x,
                     (void*)&rec_y, (void*)&rec_x, (void*)&gcur, (void*)&gprev,
                     (void*)&outp, (void*)&NT, (void*)&B, (void*)&NR };

    hipLaunchCooperativeKernel((const void*)wave_persist,
                               dim3(NSTRIP, B), dim3(NTH), args, 0, stream);
}